// Round 4
// baseline (127.821 us; speedup 1.0000x reference)
//
#include <hip/hip_runtime.h>

typedef _Float16 half8  __attribute__((ext_vector_type(8)));
typedef _Float16 half2v __attribute__((ext_vector_type(2)));
typedef float    f32x4  __attribute__((ext_vector_type(4)));

#define BB 16        // bond feature dim
#define KB 17        // bond features + bias-one feature
#define BM 128       // edges per block
#define PACK_BLKS 34
#define ZERO_BLKS 2048

// One launch: blocks [0,34) pack M2 into fragment-major f16; the rest zero d_out.
// M2[i][k] (i=0..63, k=0..1087): M2[i][b*64+j] = kernel[b][i*64+j] (b<16), bias[i*64+j] (b==16).
// Fragment layout: for (s,t,lane,e): value = M2[t*16+(lane&15)][s*32+(lane>>4)*8+e]
__global__ void prep(const float* __restrict__ kern, const float* __restrict__ bias,
                     _Float16* __restrict__ ktg, f32x4* __restrict__ out4, int n4) {
  if (blockIdx.x < PACK_BLKS) {
    int g = blockIdx.x * 256 + threadIdx.x;   // one thread per (s,t,lane)
    int s = g >> 8, t = (g >> 6) & 3, l = g & 63;
    int i = t * 16 + (l & 15);
    int k0 = s * 32 + (l >> 4) * 8;
    _Float16 v[8];
#pragma unroll
    for (int e = 0; e < 8; ++e) {
      int k = k0 + e, b = k >> 6, j = k & 63;
      float x = (b < BB) ? kern[b * 4096 + i * 64 + j] : bias[i * 64 + j];
      v[e] = (_Float16)x;
    }
    *(half8*)(ktg + (size_t)g * 8) = *(const half8*)v;
  } else {
    int i = (blockIdx.x - PACK_BLKS) * 256 + threadIdx.x;
    for (; i < n4; i += ZERO_BLKS * 256) out4[i] = (f32x4){0.f, 0.f, 0.f, 0.f};
  }
}

__device__ __forceinline__ uint32_t dup16(float x) {
  union { half2v h; uint32_t u; } c;
  _Float16 hv = (_Float16)x;
  c.h = (half2v){hv, hv};
  return c.u;
}

// Fused: transformed = X @ M2^T with X[e, b*64+j] = bond[e,b]*nb[e,j], then
// atomicAdd rows into out[src(e)]. 8 waves = 4 row-groups x 2 k-halves;
// k-halves combined via LDS reduction; B read straight from L2 (no staging).
__global__ __launch_bounds__(512, 6)
void edge_gemm(const float* __restrict__ atom, const float* __restrict__ bond,
               const int* __restrict__ pair, const _Float16* __restrict__ ktg,
               float* __restrict__ out, int E) {
  __shared__ __align__(16) char smem[32768];   // nb gather (16 KB) then k-half reduction (32 KB)
  __shared__ uint32_t bnd2[BM * KB];           // bond scales, f16 pre-duplicated {v,v}
  __shared__ int srcs[BM];

  const int tid = threadIdx.x;
  const int e0  = blockIdx.x * BM;

  { // ---- staging: 4 threads per edge row ----
    const int r = tid >> 2, q = tid & 3;
    const int e = e0 + r;
    const bool valid = e < E;
    const int nbr = valid ? pair[2 * e + 1] : 0;

    f32x4 bv = {0.f, 0.f, 0.f, 0.f};
    if (valid) bv = ((const f32x4*)(bond + (size_t)e * BB))[q];
#pragma unroll
    for (int z = 0; z < 4; ++z) bnd2[r * KB + q * 4 + z] = dup16(bv[z]);
    if (q == 3) bnd2[r * KB + 16] = dup16(valid ? 1.0f : 0.0f);  // bias-one feature
    if (q == 2) srcs[r] = valid ? pair[2 * e] : 0;

    const f32x4* arow = (const f32x4*)(atom + (size_t)nbr * 64);
#pragma unroll
    for (int cc = 0; cc < 2; ++cc) {           // 2 chunks of 8 f16 per thread
      const int c8 = q * 2 + cc;
      f32x4 x0 = {0.f,0.f,0.f,0.f}, x1 = {0.f,0.f,0.f,0.f};
      if (valid) { x0 = arow[2 * c8]; x1 = arow[2 * c8 + 1]; }
      _Float16 h[8];
      h[0] = (_Float16)x0[0]; h[1] = (_Float16)x0[1]; h[2] = (_Float16)x0[2]; h[3] = (_Float16)x0[3];
      h[4] = (_Float16)x1[0]; h[5] = (_Float16)x1[1]; h[6] = (_Float16)x1[2]; h[7] = (_Float16)x1[3];
      *(half8*)(smem + r * 128 + ((c8 ^ (r & 7)) << 4)) = *(const half8*)h;
    }
  }
  __syncthreads();

  const int lane = tid & 63, wave = tid >> 6;
  const int kh = wave & 1, mg = wave >> 1;     // k-half, row-group
  const int l15 = lane & 15, lg = lane >> 4;
  const int R0 = mg * 32 + l15, R1 = R0 + 16;  // the wave's two 16-row tiles
  const int rb0 = R0 * 128, rb1 = R1 * 128;    // LDS byte bases
  const int sw  = (l15 & 7) << 4;              // XOR swizzle (same for R0, R1)
  const char* nbb = smem;
  const _Float16* bp = ktg + (size_t)(kh * 17) * 2048 + (size_t)lane * 8;
  const int khb = kh * 8;

  f32x4 acc[2][4];
#pragma unroll
  for (int t = 0; t < 2; ++t)
#pragma unroll
    for (int n = 0; n < 4; ++n) acc[t][n] = (f32x4){0.f, 0.f, 0.f, 0.f};

  // Step (p_, i_, j_): parity p picks which 32-half chunk of nb; scale b = khb + i;
  // B fragments at local step j. All indices unroll-time constants.
#define STEP(p_, i_, j_) do {                                                   \
    const int c16 = (((p_) * 4 + lg) << 4) ^ sw;                                \
    half8 a0 = *(const half8*)(nbb + rb0 + c16);                                \
    half8 a1 = *(const half8*)(nbb + rb1 + c16);                                \
    union { uint32_t u; half2v h; } s0, s1;                                     \
    s0.u = bnd2[R0 * KB + khb + (i_)];                                          \
    s1.u = bnd2[R1 * KB + khb + (i_)];                                          \
    half2v* a0p = (half2v*)&a0; half2v* a1p = (half2v*)&a1;                     \
    _Pragma("unroll") for (int qq = 0; qq < 4; ++qq) {                          \
      a0p[qq] = a0p[qq] * s0.h; a1p[qq] = a1p[qq] * s1.h; }                     \
    _Pragma("unroll") for (int nt = 0; nt < 4; ++nt) {                          \
      const half8 bf = *(const half8*)(bp + (j_) * 2048 + nt * 512);            \
      acc[0][nt] = __builtin_amdgcn_mfma_f32_16x16x32_f16(a0, bf, acc[0][nt], 0, 0, 0); \
      acc[1][nt] = __builtin_amdgcn_mfma_f32_16x16x32_f16(a1, bf, acc[1][nt], 0, 0, 0); \
    } } while (0)

  if (kh == 0) {                               // global steps 0..16: b = j>>1
#pragma unroll
    for (int j = 0; j < 17; ++j) STEP(j & 1, j >> 1, j);
  } else {                                     // global steps 17..33: b = 8 + (j+1)>>1
#pragma unroll
    for (int j = 0; j < 17; ++j) STEP((j + 1) & 1, (j + 1) >> 1, j);
  }
#undef STEP

  __syncthreads();                             // nb region about to be reused

  // ---- k-half reduction: kh=1 stores, kh=0 adds ----
  char* red = smem;                            // [mg][lane][8 x f32x4, XOR-swizzled] = 32 KB
  if (kh == 1) {
#pragma unroll
    for (int t = 0; t < 2; ++t)
#pragma unroll
      for (int n = 0; n < 4; ++n) {
        const int i8 = t * 4 + n;
        *(f32x4*)(red + mg * 8192 + lane * 128 + ((i8 ^ (lane & 7)) << 4)) = acc[t][n];
      }
  }
  __syncthreads();
  if (kh == 0) {
#pragma unroll
    for (int t = 0; t < 2; ++t)
#pragma unroll
      for (int n = 0; n < 4; ++n) {
        const int i8 = t * 4 + n;
        f32x4 o = *(const f32x4*)(red + mg * 8192 + lane * 128 + ((i8 ^ (lane & 7)) << 4));
        acc[t][n] += o;
      }
    // ---- epilogue: segment-sum via device-scope atomics ----
#pragma unroll
    for (int t = 0; t < 2; ++t) {
#pragma unroll
      for (int rr = 0; rr < 4; ++rr) {
        const int el = mg * 32 + t * 16 + lg * 4 + rr;
        if (e0 + el < E) {
          float* dst = out + (size_t)srcs[el] * 64 + l15;
          atomicAdd(dst,      acc[t][0][rr]);
          atomicAdd(dst + 16, acc[t][1][rr]);
          atomicAdd(dst + 32, acc[t][2][rr]);
          atomicAdd(dst + 48, acc[t][3][rr]);
        }
      }
    }
  }
}

extern "C" void kernel_launch(void* const* d_in, const int* in_sizes, int n_in,
                              void* d_out, int out_size, void* d_ws, size_t ws_size,
                              hipStream_t stream) {
  const float* atom = (const float*)d_in[0];
  const float* bond = (const float*)d_in[1];
  const int*   pair = (const int*)d_in[2];
  const float* kern = (const float*)d_in[3];
  const float* bias = (const float*)d_in[4];
  float* out = (float*)d_out;
  _Float16* ktg = (_Float16*)d_ws;   // 34*4*64*8 halves = 139,264 B

  const int E  = in_sizes[1] / BB;
  const int n4 = out_size / 4;

  prep<<<PACK_BLKS + ZERO_BLKS, 256, 0, stream>>>(kern, bias, ktg, (f32x4*)out, n4);
  edge_gemm<<<(E + BM - 1) / BM, 512, 0, stream>>>(atom, bond, pair, ktg, out, E);
}

// Round 6
// 115.096 us; speedup vs baseline: 1.1106x; 1.1106x over previous
//
#include <hip/hip_runtime.h>

typedef _Float16 half8  __attribute__((ext_vector_type(8)));
typedef _Float16 half2v __attribute__((ext_vector_type(2)));
typedef float    f32x4  __attribute__((ext_vector_type(4)));

#define BB 16          // bond feature dim
#define NB_B 17        // bond features + bias-one feature
#define BM 128         // edges per block tile
#define NT 8           // 16-row tiles per BM
#define PACK_BLKS 34
#define ZERO_BLKS 1024

__device__ __forceinline__ void gll16(const void* g, void* l) {
  __builtin_amdgcn_global_load_lds(
      (const __attribute__((address_space(1))) void*)g,
      (__attribute__((address_space(3))) void*)l, 16, 0, 0);
}

// ktg layout: round r (=b), parity sp, col-frag t, lane, e:
//   half-offset = r*4096 + sp*2048 + t*512 + lane*8 + e
//   value = M2[t*16 + (lane&15)][(2r+sp)*32 + (lane>>4)*8 + e]
// where M2[i][b*64+j] = kernel[b][i*64+j] (b<16), bias[i*64+j] (b==16).
__global__ void prep(const float* __restrict__ kern, const float* __restrict__ bias,
                     _Float16* __restrict__ ktg, f32x4* __restrict__ out4, int n4) {
  if (blockIdx.x < PACK_BLKS) {
    int g = blockIdx.x * 256 + threadIdx.x;   // one thread per (s, t, lane)
    int s = g >> 8, t = (g >> 6) & 3, l = g & 63;
    int i = t * 16 + (l & 15);
    int k0 = s * 32 + (l >> 4) * 8;
    _Float16 v[8];
#pragma unroll
    for (int e = 0; e < 8; ++e) {
      int k = k0 + e, b = k >> 6, j = k & 63;
      float x = (b < BB) ? kern[b * 4096 + i * 64 + j] : bias[i * 64 + j];
      v[e] = (_Float16)x;
    }
    size_t dst = (size_t)(s >> 1) * 4096 + (size_t)(s & 1) * 2048 + t * 512 + l * 8;
    *(half8*)(ktg + dst) = *(const half8*)v;
  } else {
    int i = (blockIdx.x - PACK_BLKS) * 256 + threadIdx.x;
    for (; i < n4; i += ZERO_BLKS * 256) out4[i] = (f32x4){0.f, 0.f, 0.f, 0.f};
  }
}

// Fused: transformed = X @ M2^T with X[e, b*64+j] = bond[e,b]*nb[e,j], then
// atomicAdd rows into out[src(e)]. 4 waves; wave = one 16-col quarter x 128 rows.
// A one-shot in registers; B double-buffered in LDS via global_load_lds.
__global__ __launch_bounds__(256, 4)
void edge_gemm(const float* __restrict__ atom, const float* __restrict__ bond,
               const int* __restrict__ pair, const _Float16* __restrict__ ktg,
               float* __restrict__ out, int E) {
  __shared__ __align__(16) _Float16 nb[BM * 64];       // 16 KB, XOR-swizzled
  __shared__ __align__(16) char bbuf[2][8192];         // B double-buffer, 16 KB
  __shared__ __align__(16) _Float16 bndh[NB_B * 16 * NT]; // scales [b][l15][t], 4.25 KB
  __shared__ int srcs[BM];
  __shared__ int nbrs[BM];

  const int tid = threadIdx.x;
  const int e0  = blockIdx.x * BM;

  // ---- stage pairs ----
  if (tid < BM) {
    const int e = e0 + tid;
    const bool valid = e < E;
    int2 p2 = valid ? *(const int2*)(pair + 2 * e) : (int2){0, 0};
    srcs[tid] = p2.x;
    nbrs[tid] = p2.y;
  }
  // stage B round 0 (async, linear; per-lane offset == lane*16 within wave)
  gll16((const char*)ktg + tid * 16,        (char*)bbuf[0] + tid * 16);
  gll16((const char*)ktg + 4096 + tid * 16, (char*)bbuf[0] + 4096 + tid * 16);
  __syncthreads();   // nbrs visible for gather

  // ---- bond scales -> bndh[b][l15][t] (f16) ----
  if (tid < BM) {
    const int e = e0 + tid;
    const bool valid = e < E;
    const int wl = tid & 15, wt = tid >> 4;
    const f32x4* brow = (const f32x4*)(bond + (size_t)e * BB);
#pragma unroll
    for (int q = 0; q < 4; ++q) {
      f32x4 bv = {0.f, 0.f, 0.f, 0.f};
      if (valid) bv = brow[q];
#pragma unroll
      for (int z = 0; z < 4; ++z)
        bndh[((q * 4 + z) * 16 + wl) * NT + wt] = (_Float16)bv[z];
    }
    bndh[(16 * 16 + wl) * NT + wt] = valid ? (_Float16)1.0f : (_Float16)0.0f;
  }

  // ---- gather neighbor rows -> nb (f16, XOR-swizzled) ----
#pragma unroll
  for (int it = 0; it < 4; ++it) {
    const int idx = it * 256 + tid;          // 1024 = 128 rows x 8 chunks
    const int r = idx >> 3, c8 = idx & 7;
    const int nbr = nbrs[r];
    const bool valid = (e0 + r) < E;
    f32x4 x0 = {0.f,0.f,0.f,0.f}, x1 = {0.f,0.f,0.f,0.f};
    if (valid) {
      const f32x4* arow = (const f32x4*)(atom + (size_t)nbr * 64);
      x0 = arow[2 * c8]; x1 = arow[2 * c8 + 1];
    }
    _Float16 h[8];
    h[0] = (_Float16)x0[0]; h[1] = (_Float16)x0[1]; h[2] = (_Float16)x0[2]; h[3] = (_Float16)x0[3];
    h[4] = (_Float16)x1[0]; h[5] = (_Float16)x1[1]; h[6] = (_Float16)x1[2]; h[7] = (_Float16)x1[3];
    *(half8*)((char*)nb + r * 128 + ((c8 ^ (r & 7)) << 4)) = *(const half8*)h;
  }
  __syncthreads();   // nb, bndh, bbuf[0] all ready (barrier drains gll16)

  const int lane = tid & 63, wave = tid >> 6;   // wave = col-quarter
  const int l15 = lane & 15, lg = lane >> 4;

  // ---- one-shot A fragments into registers ----
  half8 a[NT][2];
#pragma unroll
  for (int t = 0; t < NT; ++t) {
    const int r = t * 16 + l15;
    const int rb = r * 128, sw = (r & 7) << 4;
#pragma unroll
    for (int p = 0; p < 2; ++p)
      a[t][p] = *(const half8*)((const char*)nb + rb + (((p * 4 + lg) << 4) ^ sw));
  }

  f32x4 acc[NT];
#pragma unroll
  for (int t = 0; t < NT; ++t) acc[t] = (f32x4){0.f, 0.f, 0.f, 0.f};

  // ---- K loop: 17 rounds x (2 k-steps of 32); stage-early, one barrier/round ----
  for (int b = 0; b < NB_B; ++b) {
    if (b + 1 < NB_B) {
      const char* src = (const char*)ktg + (size_t)(b + 1) * 8192;
      char* dst = (char*)bbuf[(b + 1) & 1];
      gll16(src + tid * 16,        dst + tid * 16);
      gll16(src + 4096 + tid * 16, dst + 4096 + tid * 16);
    }
    const half8 sv = *(const half8*)&bndh[(b * 16 + l15) * NT];  // 8 tile-scales
    const char* bp = (const char*)bbuf[b & 1] + wave * 1024 + lane * 16;
#pragma unroll
    for (int sp = 0; sp < 2; ++sp) {
      const half8 bf = *(const half8*)(bp + sp * 4096);
#pragma unroll
      for (int t = 0; t < NT; ++t) {
        const _Float16 s = sv[t];
        const half2v sc = {s, s};
        half8 as = a[t][sp];
        half2v* ap = (half2v*)&as;
#pragma unroll
        for (int q = 0; q < 4; ++q) ap[q] = ap[q] * sc;   // X = bond * nb
        acc[t] = __builtin_amdgcn_mfma_f32_16x16x32_f16(as, bf, acc[t], 0, 0, 0);
      }
    }
    __syncthreads();   // all reads of bbuf[b&1] done; next stage may overwrite it
  }

  // ---- epilogue: segment-sum via device-scope atomics ----
#pragma unroll
  for (int t = 0; t < NT; ++t) {
#pragma unroll
    for (int rr = 0; rr < 4; ++rr) {
      const int el = t * 16 + lg * 4 + rr;
      if (e0 + el < E)
        atomicAdd(out + (size_t)srcs[el] * 64 + wave * 16 + l15, acc[t][rr]);
    }
  }
}

extern "C" void kernel_launch(void* const* d_in, const int* in_sizes, int n_in,
                              void* d_out, int out_size, void* d_ws, size_t ws_size,
                              hipStream_t stream) {
  const float* atom = (const float*)d_in[0];
  const float* bond = (const float*)d_in[1];
  const int*   pair = (const int*)d_in[2];
  const float* kern = (const float*)d_in[3];
  const float* bias = (const float*)d_in[4];
  float* out = (float*)d_out;
  _Float16* ktg = (_Float16*)d_ws;   // 69,632 halves = 139,264 B

  const int E  = in_sizes[1] / BB;
  const int n4 = out_size / 4;

  prep<<<PACK_BLKS + ZERO_BLKS, 256, 0, stream>>>(kern, bias, ktg, (f32x4*)out, n4);
  edge_gemm<<<(E + BM - 1) / BM, 256, 0, stream>>>(atom, bond, pair, ktg, out, E);
}

// Round 7
// 110.895 us; speedup vs baseline: 1.1526x; 1.0379x over previous
//
#include <hip/hip_runtime.h>

typedef _Float16 half8  __attribute__((ext_vector_type(8)));
typedef _Float16 half4v __attribute__((ext_vector_type(4)));
typedef _Float16 half2v __attribute__((ext_vector_type(2)));
typedef float    f32x4  __attribute__((ext_vector_type(4)));

#define BB 16          // bond feature dim
#define NB_B 17        // bond features + bias-one feature
#define BM 128         // edges per block tile
#define NT 8           // 16-row tiles per BM
#define PACK_BLKS 34
#define ZERO_BLKS 1024

// ktg layout: round r (=b), parity sp, col-frag t, lane, e:
//   half-offset = r*4096 + sp*2048 + t*512 + lane*8 + e
//   value = M2[t*16 + (lane&15)][(2r+sp)*32 + (lane>>4)*8 + e]
// where M2[i][b*64+j] = kernel[b][i*64+j] (b<16), bias[i*64+j] (b==16).
__global__ void prep(const float* __restrict__ kern, const float* __restrict__ bias,
                     _Float16* __restrict__ ktg, f32x4* __restrict__ out4, int n4) {
  if (blockIdx.x < PACK_BLKS) {
    int g = blockIdx.x * 256 + threadIdx.x;   // one thread per (s, t, lane)
    int s = g >> 8, t = (g >> 6) & 3, l = g & 63;
    int i = t * 16 + (l & 15);
    int k0 = s * 32 + (l >> 4) * 8;
    _Float16 v[8];
#pragma unroll
    for (int e = 0; e < 8; ++e) {
      int k = k0 + e, b = k >> 6, j = k & 63;
      float x = (b < BB) ? kern[b * 4096 + i * 64 + j] : bias[i * 64 + j];
      v[e] = (_Float16)x;
    }
    size_t dst = (size_t)(s >> 1) * 4096 + (size_t)(s & 1) * 2048 + t * 512 + l * 8;
    *(half8*)(ktg + dst) = *(const half8*)v;
  } else {
    int i = (blockIdx.x - PACK_BLKS) * 256 + threadIdx.x;
    for (; i < n4; i += ZERO_BLKS * 256) out4[i] = (f32x4){0.f, 0.f, 0.f, 0.f};
  }
}

// Fused: transformed = X @ M2^T with X[e, b*64+j] = bond[e,b]*nb[e,j], then
// atomicAdd rows into out[src(e)].
// 4 waves in 2(row)x2(col): wave = 64 rows x 32 cols. A one-shot in registers;
// B straight from L2 into registers, 3-round lookahead; NO barriers in K loop.
__global__ __launch_bounds__(256, 3)
void edge_gemm(const float* __restrict__ atom, const float* __restrict__ bond,
               const int* __restrict__ pair, const _Float16* __restrict__ ktg,
               float* __restrict__ out, int E) {
  __shared__ __align__(16) _Float16 nb[BM * 64];          // 16 KB, XOR-swizzled
  __shared__ __align__(16) _Float16 bndh[NB_B * 16 * NT]; // scales [b][l15][t], 4.25 KB
  __shared__ int srcs[BM];
  __shared__ int nbrs[BM];

  const int tid = threadIdx.x;
  const int e0  = blockIdx.x * BM;

  // ---- stage pairs ----
  if (tid < BM) {
    const int e = e0 + tid;
    const bool valid = e < E;
    int2 p2 = valid ? *(const int2*)(pair + 2 * e) : (int2){0, 0};
    srcs[tid] = p2.x;
    nbrs[tid] = p2.y;
  }
  __syncthreads();   // nbrs visible for gather

  // ---- bond scales -> bndh[b][l15][t] (f16) ----
  if (tid < BM) {
    const int e = e0 + tid;
    const bool valid = e < E;
    const int wl = tid & 15, wt = tid >> 4;
    const f32x4* brow = (const f32x4*)(bond + (size_t)e * BB);
#pragma unroll
    for (int q = 0; q < 4; ++q) {
      f32x4 bv = {0.f, 0.f, 0.f, 0.f};
      if (valid) bv = brow[q];
#pragma unroll
      for (int z = 0; z < 4; ++z)
        bndh[((q * 4 + z) * 16 + wl) * NT + wt] = (_Float16)bv[z];
    }
    bndh[(16 * 16 + wl) * NT + wt] = valid ? (_Float16)1.0f : (_Float16)0.0f;
  }

  // ---- gather neighbor rows -> nb (f16, XOR-swizzled) ----
#pragma unroll
  for (int it = 0; it < 4; ++it) {
    const int idx = it * 256 + tid;          // 1024 = 128 rows x 8 chunks
    const int r = idx >> 3, c8 = idx & 7;
    const int nbr = nbrs[r];
    const bool valid = (e0 + r) < E;
    f32x4 x0 = {0.f,0.f,0.f,0.f}, x1 = {0.f,0.f,0.f,0.f};
    if (valid) {
      const f32x4* arow = (const f32x4*)(atom + (size_t)nbr * 64);
      x0 = arow[2 * c8]; x1 = arow[2 * c8 + 1];
    }
    _Float16 h[8];
    h[0] = (_Float16)x0[0]; h[1] = (_Float16)x0[1]; h[2] = (_Float16)x0[2]; h[3] = (_Float16)x0[3];
    h[4] = (_Float16)x1[0]; h[5] = (_Float16)x1[1]; h[6] = (_Float16)x1[2]; h[7] = (_Float16)x1[3];
    *(half8*)((char*)nb + r * 128 + ((c8 ^ (r & 7)) << 4)) = *(const half8*)h;
  }
  __syncthreads();   // nb + bndh ready — LAST barrier in the kernel

  const int lane = tid & 63, wave = tid >> 6;
  const int wm = wave >> 1, wn = wave & 1;   // row-half, col-half
  const int l15 = lane & 15, lg = lane >> 4;

  // ---- one-shot A fragments into registers (4 row-tiles x 2 k-parities) ----
  half8 a[4][2];
#pragma unroll
  for (int t = 0; t < 4; ++t) {
    const int r = wm * 64 + t * 16 + l15;
    const int rb = r * 128, sw = (r & 7) << 4;
#pragma unroll
    for (int p = 0; p < 2; ++p)
      a[t][p] = *(const half8*)((const char*)nb + rb + (((p * 4 + lg) << 4) ^ sw));
  }

  f32x4 acc[4][2];
#pragma unroll
  for (int t = 0; t < 4; ++t) {
    acc[t][0] = (f32x4){0.f, 0.f, 0.f, 0.f};
    acc[t][1] = (f32x4){0.f, 0.f, 0.f, 0.f};
  }

  // ---- K loop: 17 rounds, fully unrolled, B in regs with 3-round rotation ----
  const _Float16* bp  = ktg + (size_t)wn * 1024 + (size_t)lane * 8;
  const _Float16* scp = &bndh[l15 * NT + wm * 4];

  half8 bf[3][4];   // [slot][sp*2+cc]
#pragma unroll
  for (int rr = 0; rr < 3; ++rr)
#pragma unroll
    for (int f = 0; f < 4; ++f)
      bf[rr][f] = *(const half8*)(bp + rr * 4096 + (f >> 1) * 2048 + (f & 1) * 512);

#pragma unroll
  for (int r = 0; r < NB_B; ++r) {
    const int slot = r % 3;
    const half4v sv = *(const half4v*)(scp + r * 128);   // 4 row-tile scales
#pragma unroll
    for (int t = 0; t < 4; ++t) {
      const half2v sc = {sv[t], sv[t]};
      half8 a0 = a[t][0], a1 = a[t][1];
      half2v* a0p = (half2v*)&a0; half2v* a1p = (half2v*)&a1;
#pragma unroll
      for (int q = 0; q < 4; ++q) { a0p[q] = a0p[q] * sc; a1p[q] = a1p[q] * sc; }
      acc[t][0] = __builtin_amdgcn_mfma_f32_16x16x32_f16(a0, bf[slot][0], acc[t][0], 0, 0, 0);
      acc[t][1] = __builtin_amdgcn_mfma_f32_16x16x32_f16(a0, bf[slot][1], acc[t][1], 0, 0, 0);
      acc[t][0] = __builtin_amdgcn_mfma_f32_16x16x32_f16(a1, bf[slot][2], acc[t][0], 0, 0, 0);
      acc[t][1] = __builtin_amdgcn_mfma_f32_16x16x32_f16(a1, bf[slot][3], acc[t][1], 0, 0, 0);
    }
    if (r + 3 < NB_B) {
#pragma unroll
      for (int f = 0; f < 4; ++f)
        bf[slot][f] = *(const half8*)(bp + (r + 3) * 4096 + (f >> 1) * 2048 + (f & 1) * 512);
    }
  }

  // ---- epilogue: segment-sum via device-scope atomics ----
#pragma unroll
  for (int t = 0; t < 4; ++t) {
#pragma unroll
    for (int rr = 0; rr < 4; ++rr) {
      const int el = wm * 64 + t * 16 + lg * 4 + rr;
      if (e0 + el < E) {
        float* dst = out + (size_t)srcs[el] * 64 + wn * 32 + l15;
        atomicAdd(dst,      acc[t][0][rr]);
        atomicAdd(dst + 16, acc[t][1][rr]);
      }
    }
  }
}

extern "C" void kernel_launch(void* const* d_in, const int* in_sizes, int n_in,
                              void* d_out, int out_size, void* d_ws, size_t ws_size,
                              hipStream_t stream) {
  const float* atom = (const float*)d_in[0];
  const float* bond = (const float*)d_in[1];
  const int*   pair = (const int*)d_in[2];
  const float* kern = (const float*)d_in[3];
  const float* bias = (const float*)d_in[4];
  float* out = (float*)d_out;
  _Float16* ktg = (_Float16*)d_ws;   // 69,632 halves = 139,264 B

  const int E  = in_sizes[1] / BB;
  const int n4 = out_size / 4;

  prep<<<PACK_BLKS + ZERO_BLKS, 256, 0, stream>>>(kern, bias, ktg, (f32x4*)out, n4);
  edge_gemm<<<(E + BM - 1) / BM, 256, 0, stream>>>(atom, bond, pair, ktg, out, E);
}

// Round 8
// 109.132 us; speedup vs baseline: 1.1713x; 1.0162x over previous
//
#include <hip/hip_runtime.h>

typedef _Float16 half8  __attribute__((ext_vector_type(8)));
typedef _Float16 half2v __attribute__((ext_vector_type(2)));
typedef float    f32x4  __attribute__((ext_vector_type(4)));

#define BB 16          // bond feature dim
#define NB_B 17        // bond features + bias-one feature
#define BM 64          // edges per block tile
#define PACK_BLKS 34
#define ZERO_BLKS 1024

__device__ __forceinline__ void gll16(const void* g, void* l) {
  __builtin_amdgcn_global_load_lds(
      (const __attribute__((address_space(1))) void*)g,
      (__attribute__((address_space(3))) void*)l, 16, 0, 0);
}

// ktg layout: round r (=b), parity sp, col-frag t, lane, e:
//   half-offset = r*4096 + sp*2048 + t*512 + lane*8 + e
//   value = M2[t*16 + (lane&15)][(2r+sp)*32 + (lane>>4)*8 + e]
// where M2[i][b*64+j] = kernel[b][i*64+j] (b<16), bias[i*64+j] (b==16).
__global__ void prep(const float* __restrict__ kern, const float* __restrict__ bias,
                     _Float16* __restrict__ ktg, f32x4* __restrict__ out4, int n4) {
  if (blockIdx.x < PACK_BLKS) {
    int g = blockIdx.x * 256 + threadIdx.x;   // one thread per (s, t, lane)
    int s = g >> 8, t = (g >> 6) & 3, l = g & 63;
    int i = t * 16 + (l & 15);
    int k0 = s * 32 + (l >> 4) * 8;
    _Float16 v[8];
#pragma unroll
    for (int e = 0; e < 8; ++e) {
      int k = k0 + e, b = k >> 6, j = k & 63;
      float x = (b < BB) ? kern[b * 4096 + i * 64 + j] : bias[i * 64 + j];
      v[e] = (_Float16)x;
    }
    size_t dst = (size_t)(s >> 1) * 4096 + (size_t)(s & 1) * 2048 + t * 512 + l * 8;
    *(half8*)(ktg + dst) = *(const half8*)v;
  } else {
    int i = (blockIdx.x - PACK_BLKS) * 256 + threadIdx.x;
    for (; i < n4; i += ZERO_BLKS * 256) out4[i] = (f32x4){0.f, 0.f, 0.f, 0.f};
  }
}

// Fused: transformed = X @ M2^T with X[e, b*64+j] = bond[e,b]*nb[e,j], then
// atomicAdd rows into out[src(e)].
// BM=64, 4 waves in 2(row)x2(col): wave = 32 rows x 32 cols.
// A one-shot in registers; B double-buffered in LDS (stage-early, 1 barrier/round).
__global__ __launch_bounds__(256, 5)
void edge_gemm(const float* __restrict__ atom, const float* __restrict__ bond,
               const int* __restrict__ pair, const _Float16* __restrict__ ktg,
               float* __restrict__ out, int E) {
  __shared__ __align__(16) _Float16 nb[BM * 64];     // 8 KB, XOR-swizzled
  __shared__ __align__(16) char bbuf[2][8192];       // B double-buffer, 16 KB
  __shared__ _Float16 bndh[NB_B * BM];               // scales [b][row], 2.1 KB
  __shared__ int srcs[BM];
  __shared__ int nbrs[BM];

  const int tid = threadIdx.x;
  const int e0  = blockIdx.x * BM;

  // ---- stage pairs + B round 0 ----
  if (tid < BM) {
    const int e = e0 + tid;
    const bool valid = e < E;
    int2 p2 = valid ? *(const int2*)(pair + 2 * e) : (int2){0, 0};
    srcs[tid] = p2.x;
    nbrs[tid] = p2.y;
  }
  gll16((const char*)ktg + tid * 16,        (char*)bbuf[0] + tid * 16);
  gll16((const char*)ktg + 4096 + tid * 16, (char*)bbuf[0] + 4096 + tid * 16);
  __syncthreads();   // nbrs visible (also drains the B0 stage — fine)

  // ---- bond scales -> bndh[b*64 + row] (f16) ----
  if (tid < BM) {
    const int e = e0 + tid;
    const bool valid = e < E;
    const f32x4* brow = (const f32x4*)(bond + (size_t)e * BB);
#pragma unroll
    for (int q = 0; q < 4; ++q) {
      f32x4 bv = {0.f, 0.f, 0.f, 0.f};
      if (valid) bv = brow[q];
#pragma unroll
      for (int z = 0; z < 4; ++z) bndh[(q * 4 + z) * BM + tid] = (_Float16)bv[z];
    }
    bndh[16 * BM + tid] = valid ? (_Float16)1.0f : (_Float16)0.0f;  // bias-one
  }

  // ---- gather neighbor rows -> nb (f16, XOR-swizzled) ----
#pragma unroll
  for (int it = 0; it < 2; ++it) {
    const int idx = it * 256 + tid;          // 512 = 64 rows x 8 chunks
    const int r = idx >> 3, c8 = idx & 7;
    const int nbr = nbrs[r];
    const bool valid = (e0 + r) < E;
    f32x4 x0 = {0.f,0.f,0.f,0.f}, x1 = {0.f,0.f,0.f,0.f};
    if (valid) {
      const f32x4* arow = (const f32x4*)(atom + (size_t)nbr * 64);
      x0 = arow[2 * c8]; x1 = arow[2 * c8 + 1];
    }
    _Float16 h[8];
    h[0] = (_Float16)x0[0]; h[1] = (_Float16)x0[1]; h[2] = (_Float16)x0[2]; h[3] = (_Float16)x0[3];
    h[4] = (_Float16)x1[0]; h[5] = (_Float16)x1[1]; h[6] = (_Float16)x1[2]; h[7] = (_Float16)x1[3];
    *(half8*)((char*)nb + r * 128 + ((c8 ^ (r & 7)) << 4)) = *(const half8*)h;
  }
  __syncthreads();   // nb + bndh + bbuf[0] ready

  const int lane = tid & 63, wave = tid >> 6;
  const int wm = wave >> 1, wn = wave & 1;   // row-half, col-half
  const int l15 = lane & 15, lg = lane >> 4;

  // ---- one-shot A fragments into registers (2 row-tiles x 2 k-parities) ----
  half8 a[2][2];
#pragma unroll
  for (int t = 0; t < 2; ++t) {
    const int r = wm * 32 + t * 16 + l15;
    const int rb = r * 128, sw = (r & 7) << 4;
#pragma unroll
    for (int p = 0; p < 2; ++p)
      a[t][p] = *(const half8*)((const char*)nb + rb + (((p * 4 + lg) << 4) ^ sw));
  }

  f32x4 acc[2][2];
#pragma unroll
  for (int t = 0; t < 2; ++t)
#pragma unroll
    for (int n = 0; n < 2; ++n) acc[t][n] = (f32x4){0.f, 0.f, 0.f, 0.f};

  // ---- K loop: 17 rounds; stage-early, compute from LDS, one barrier/round ----
  for (int b = 0; b < NB_B; ++b) {
    if (b + 1 < NB_B) {
      const char* src = (const char*)ktg + (size_t)(b + 1) * 8192;
      char* dst = (char*)bbuf[(b + 1) & 1];
      gll16(src + tid * 16,        dst + tid * 16);
      gll16(src + 4096 + tid * 16, dst + 4096 + tid * 16);
    }
    const _Float16 s0 = bndh[b * BM + wm * 32 + l15];
    const _Float16 s1 = bndh[b * BM + wm * 32 + 16 + l15];
    const half2v sc0 = {s0, s0}, sc1 = {s1, s1};
    const char* bp = (const char*)bbuf[b & 1] + (size_t)(wn * 2) * 1024 + lane * 16;
#pragma unroll
    for (int sp = 0; sp < 2; ++sp) {
      half8 a0 = a[0][sp], a1 = a[1][sp];
      half2v* a0p = (half2v*)&a0; half2v* a1p = (half2v*)&a1;
#pragma unroll
      for (int q = 0; q < 4; ++q) { a0p[q] = a0p[q] * sc0; a1p[q] = a1p[q] * sc1; }
#pragma unroll
      for (int nt = 0; nt < 2; ++nt) {
        const half8 bf = *(const half8*)(bp + sp * 4096 + nt * 1024);
        acc[0][nt] = __builtin_amdgcn_mfma_f32_16x16x32_f16(a0, bf, acc[0][nt], 0, 0, 0);
        acc[1][nt] = __builtin_amdgcn_mfma_f32_16x16x32_f16(a1, bf, acc[1][nt], 0, 0, 0);
      }
    }
    __syncthreads();   // all reads of bbuf[b&1] done; drains next stage's vmcnt
  }

  // ---- epilogue: segment-sum via device-scope atomics ----
#pragma unroll
  for (int t = 0; t < 2; ++t) {
#pragma unroll
    for (int rr = 0; rr < 4; ++rr) {
      const int el = wm * 32 + t * 16 + lg * 4 + rr;
      if (e0 + el < E) {
        float* dst = out + (size_t)srcs[el] * 64 + wn * 32 + l15;
        atomicAdd(dst,      acc[t][0][rr]);
        atomicAdd(dst + 16, acc[t][1][rr]);
      }
    }
  }
}

extern "C" void kernel_launch(void* const* d_in, const int* in_sizes, int n_in,
                              void* d_out, int out_size, void* d_ws, size_t ws_size,
                              hipStream_t stream) {
  const float* atom = (const float*)d_in[0];
  const float* bond = (const float*)d_in[1];
  const int*   pair = (const int*)d_in[2];
  const float* kern = (const float*)d_in[3];
  const float* bias = (const float*)d_in[4];
  float* out = (float*)d_out;
  _Float16* ktg = (_Float16*)d_ws;   // 69,632 halves = 139,264 B

  const int E  = in_sizes[1] / BB;
  const int n4 = out_size / 4;

  prep<<<PACK_BLKS + ZERO_BLKS, 256, 0, stream>>>(kern, bias, ktg, (f32x4*)out, n4);
  edge_gemm<<<(E + BM - 1) / BM, 256, 0, stream>>>(atom, bond, pair, ktg, out, E);
}